// Round 1
// 285.526 us; speedup vs baseline: 1.1654x; 1.1654x over previous
//
#include <hip/hip_runtime.h>
#include <hip/hip_bf16.h>

// MultiHeadedAttention2: dual-stream MHA with elementwise-max merge of the two
// softmax attention maps. Inputs fp32 (detected & converted to bf16 in ws);
// internal compute bf16 MFMA; OUTPUT WRITTEN AS FP32 (reference output dtype).
//
// Pipeline (4 dispatches):
//  0) convert_inputs: probe each tensor (bf16-view of first 512 elems; fp32
//     bits viewed as bf16 show >1e4/NaN values), convert/copy to bf16 in ws.
//  1) qkv_gemm : 6 projections. Q,K -> [B,H,S,64] bf16, V -> [B,H,64,S] bf16.
//                Q pre-scaled by 0.125*log2(e) so softmax uses native v_exp_f32.
//  2) attn_merged: two-pass merged softmax, deep-pipelined:
//                - raw s_barrier (no vmcnt(0) drain) + T14 async-stage split:
//                  next K/V tile's global loads stay in flight across the whole
//                  compute phase; only lgkmcnt(0) is waited before the barrier.
//                - Ps (merged probs) round-trip is wave-local -> no block
//                  barrier, just lgkmcnt(0)+sched_barrier.
//                - XCD-chunked block swizzle: 8 q-tiles of one head per XCD.
//  3) out_gemm : output projections + bias -> d_out (FP32, rgb then flow).

typedef unsigned short u16;
typedef __attribute__((ext_vector_type(8))) short short8;   // 8 x bf16 (4 VGPRs)
typedef __attribute__((ext_vector_type(4))) float floatx4;  // MFMA accumulator

#define B_DIM 8
#define S_DIM 1024
#define H_DIM 8
#define DK 64
#define DMODEL 512
#define NTOK (B_DIM * S_DIM)                 // 8192 tokens
#define SEG ((size_t)NTOK * DMODEL)          // 4194304 elems per tensor
#define WSEG ((size_t)DMODEL * DMODEL)       // 262144 elems per weight

#define SCHED_FENCE() __builtin_amdgcn_sched_barrier(0)
#define LGKM0() asm volatile("s_waitcnt lgkmcnt(0)" ::: "memory")
#define BARRIER() __builtin_amdgcn_s_barrier()

__device__ __forceinline__ floatx4 mfma_bf16(short8 a, short8 b, floatx4 c) {
  return __builtin_amdgcn_mfma_f32_16x16x32_bf16(a, b, c, 0, 0, 0);
}

__device__ __forceinline__ u16 f32_to_bf16_rne(float f) {
  unsigned u = __float_as_uint(f);
  unsigned r = u + 0x7FFFu + ((u >> 16) & 1u);
  return (u16)(r >> 16);
}

__device__ __forceinline__ float bf16_bits_to_f32(u16 u) {
  return __uint_as_float(((unsigned)u) << 16);
}

// async global->LDS, 16B per lane; lds is the wave-uniform base
// (HW deposits lane i at lds + i*16).
__device__ __forceinline__ void async_cp16(const u16* g, u16* lds) {
  __builtin_amdgcn_global_load_lds(
      (__attribute__((address_space(1))) void*)(const_cast<u16*>(g)),
      (__attribute__((address_space(3))) void*)(lds), 16, 0, 0);
}

// ---------------------------------------------------------------------------
// Kernel 0: dtype-detect + convert to bf16. Each block handles one 65536-elem
// chunk of one tensor; wave 0 probes the tensor's first 512 elems (bf16 view)
// to decide fp32 vs bf16 (deterministic, same verdict for all blocks).
// ---------------------------------------------------------------------------
#define NT_CONV 18
struct ConvParams {
  const void* src[NT_CONV];
  u16* dst[NT_CONV];
  int n[NT_CONV];
  int coff[NT_CONV + 1];   // prefix sums of chunk counts
};

__global__ __launch_bounds__(256) void convert_inputs(ConvParams p) {
  __shared__ int flag_f32;
  const int blk = blockIdx.x;
  int t = 0;
  while (t + 1 < NT_CONV && blk >= p.coff[t + 1]) ++t;
  const int lc = blk - p.coff[t];
  const int n = p.n[t];
  const int tid = threadIdx.x;

  if (tid < 64) {
    const u16* s = (const u16*)p.src[t];
    int bad = 0;
#pragma unroll
    for (int j = 0; j < 8; ++j) {
      float f = bf16_bits_to_f32(s[tid * 8 + j]);
      bad |= !(fabsf(f) < 1e4f);   // catches huge AND NaN
    }
    bad |= __shfl_xor(bad, 1);
    bad |= __shfl_xor(bad, 2);
    bad |= __shfl_xor(bad, 4);
    bad |= __shfl_xor(bad, 8);
    bad |= __shfl_xor(bad, 16);
    bad |= __shfl_xor(bad, 32);
    if (tid == 0) flag_f32 = bad;
  }
  __syncthreads();
  const int is_f32 = flag_f32;
  const int base = lc * 65536;

  for (int it = 0; it < 32; ++it) {
    const int idx = base + (it * 256 + tid) * 8;
    if (idx + 8 > n) break;
    if (!is_f32) {
      *(short8*)&p.dst[t][idx] = *(const short8*)&((const u16*)p.src[t])[idx];
    } else {
      const float* s = (const float*)p.src[t] + idx;
      short8 o;
#pragma unroll
      for (int j = 0; j < 8; ++j) o[j] = (short)f32_to_bf16_rne(s[j]);
      *(short8*)&p.dst[t][idx] = o;
    }
  }
}

// ---------------------------------------------------------------------------
// 128x128 NT GEMM mainloop: C += A[m0:+128, :K] * W[n0:+128, :K]^T
// A,W row-major bf16, lda = ldw = K. 256 threads / 4 waves (2x2), each wave a
// 64x64 sub-tile as 4x4 mfma_f32_16x16x32_bf16. Single-buffer LDS (m97-style),
// global_load_lds width=16 staging.
// ---------------------------------------------------------------------------
__device__ __forceinline__ void gemm128_mainloop(
    const u16* __restrict__ A, const u16* __restrict__ W,
    int m0, int n0, int K, u16* ldsA, u16* ldsB, floatx4 acc[4][4]) {
  const int tid = threadIdx.x;
  const int lane = tid & 63;
  const int wid = tid >> 6;
  const int wm = wid >> 1, wn = wid & 1;
  const int r = lane & 15, g = lane >> 4;

  const int stg_row = wid * 32 + (lane >> 2);
  const int stg_col = (lane & 3) * 8;

  const u16* ga0 = A + (size_t)(m0 + stg_row) * K + stg_col;
  const u16* ga1 = A + (size_t)(m0 + stg_row + 16) * K + stg_col;
  const u16* gb0 = W + (size_t)(n0 + stg_row) * K + stg_col;
  const u16* gb1 = W + (size_t)(n0 + stg_row + 16) * K + stg_col;
  u16* la0 = ldsA + (wid * 32) * 32;       // wave-uniform LDS bases
  u16* la1 = ldsA + (wid * 32 + 16) * 32;
  u16* lb0 = ldsB + (wid * 32) * 32;
  u16* lb1 = ldsB + (wid * 32 + 16) * 32;

  for (int k0 = 0; k0 < K; k0 += 32) {
    if (k0) __syncthreads();                  // protect LDS from prev readers
    async_cp16(ga0 + k0, la0);
    async_cp16(ga1 + k0, la1);
    async_cp16(gb0 + k0, lb0);
    async_cp16(gb1 + k0, lb1);
    __syncthreads();                          // drains vmcnt before ds_read

    short8 a[4], b[4];
#pragma unroll
    for (int i = 0; i < 4; ++i)
      a[i] = *(const short8*)&ldsA[(wm * 64 + i * 16 + r) * 32 + g * 8];
#pragma unroll
    for (int j = 0; j < 4; ++j)
      b[j] = *(const short8*)&ldsB[(wn * 64 + j * 16 + r) * 32 + g * 8];
#pragma unroll
    for (int i = 0; i < 4; ++i)
#pragma unroll
      for (int j = 0; j < 4; ++j)
        acc[i][j] = mfma_bf16(a[i], b[j], acc[i][j]);
  }
}

// ---------------------------------------------------------------------------
// Kernel 1: QKV projections. grid = (64, 12, 2).
// ---------------------------------------------------------------------------
struct QkvParams {
  const u16* X[2];
  const u16* W[2][3];
  const u16* Bias[2][3];
  u16* Out[2][3];
};

__global__ __launch_bounds__(256) void qkv_gemm(QkvParams p) {
  __shared__ u16 ldsA[128 * 32];
  __shared__ u16 ldsB[128 * 32];
  const int z = blockIdx.z;
  const int wi = blockIdx.y >> 2;            // 0=Q 1=K 2=V
  const int n0 = (blockIdx.y & 3) * 128;
  const int m0 = blockIdx.x * 128;

  floatx4 acc[4][4];
  const floatx4 z4 = {0.f, 0.f, 0.f, 0.f};
#pragma unroll
  for (int i = 0; i < 4; ++i)
#pragma unroll
    for (int j = 0; j < 4; ++j) acc[i][j] = z4;

  gemm128_mainloop(p.X[z], p.W[z][wi], m0, n0, DMODEL, ldsA, ldsB, acc);

  const int tid = threadIdx.x, lane = tid & 63, wid = tid >> 6;
  const int wm = wid >> 1, wn = wid & 1, r = lane & 15, g = lane >> 4;
  const u16* bias = p.Bias[z][wi];
  u16* out = p.Out[z][wi];
  const float qscale = 0.125f * 1.4426950408889634f;  // 1/sqrt(dk) * log2(e)

#pragma unroll
  for (int j = 0; j < 4; ++j) {
    const int c = n0 + wn * 64 + j * 16 + r;          // output col in [0,512)
    const float bv = bf16_bits_to_f32(bias[c]);
    const int h = c >> 6, d = c & 63;
#pragma unroll
    for (int i = 0; i < 4; ++i) {
      const int row0 = m0 + wm * 64 + i * 16 + g * 4;
#pragma unroll
      for (int ii = 0; ii < 4; ++ii) {
        const int row = row0 + ii;                    // token index
        const int bb = row >> 10, ss = row & 1023;
        float v = acc[i][j][ii] + bv;
        size_t addr;
        if (wi == 0) {                                // Q: [B,H,S,64], scaled
          v *= qscale;
          addr = (((size_t)(bb * H_DIM + h)) * S_DIM + ss) * DK + d;
        } else if (wi == 1) {                         // K: [B,H,S,64]
          addr = (((size_t)(bb * H_DIM + h)) * S_DIM + ss) * DK + d;
        } else {                                      // V^T: [B,H,64,S]
          addr = (((size_t)(bb * H_DIM + h)) * DK + d) * S_DIM + ss;
        }
        out[addr] = f32_to_bf16_rne(v);
      }
    }
  }
}

// ---------------------------------------------------------------------------
// Kernel 2: merged-softmax attention. grid = (512) 1-D, XCD-chunked swizzle.
// Per block: 128 q rows of one (b,h); 4 waves; wave w owns rows [w*32,w*32+32).
// LDS tiles padded to 72-elem rows: 2-way bank aliasing only (free, m136).
//
// Pipeline per K-tile (both passes):
//   [raw s_barrier]                 -- prev readers done (NO vmcnt drain)
//   ds_write staged regs -> LDS     -- implicit vmcnt wait on THOSE regs only
//   issue next tile's global loads  -- in flight across the whole compute
//   lgkmcnt(0); [raw s_barrier]     -- all waves' tile writes visible
//   compute                         -- loads for kt+1 land under this
// ---------------------------------------------------------------------------
struct AttnParams {
  const u16* Q[2];
  const u16* K[2];
  const u16* Vt[2];
  u16* O[2];
};

__global__ __launch_bounds__(256) void attn_merged(AttnParams p) {
  __shared__ u16 Ks[2][64 * 72];   // [stream][key][d pad72]
  __shared__ u16 Vs[2][64 * 72];   // [stream][d][key pad72]  (V^T tile)
  __shared__ u16 Ps[128 * 72];     // merged probs [q][key pad72] (wave-local)

  const int tid = threadIdx.x;
  const int lane = tid & 63;
  const int wid = tid >> 6;
  const int r = lane & 15, g = lane >> 4;

  // XCD-chunked bijective swizzle (512 = 8 XCD * 64): HW assigns XCD = lin%8;
  // each XCD gets 64 consecutive work items = 8 whole heads -> K/V working
  // set ~6 MB/XCD (vs 48 MB unswizzled) stays in its 4 MiB L2.
  const int lin = blockIdx.x;
  const int w = (lin & 7) * 64 + (lin >> 3);
  const int bh = w >> 3;                 // (b*8+h)
  const int q0 = (w & 7) * 128;          // q-tile base
  const size_t hbase = (size_t)bh * S_DIM * DK;

  const int srow = tid >> 3;             // staging row 0..31 (and +32)
  const int sch = (tid & 7) * 8;         // staging col chunk (8 bf16 = 16 B)

  // Q fragments (A-operand): lane holds Q[row = q0+w*32+mt*16+r][kc*32+g*8+j]
  short8 qf[2][2][2];
#pragma unroll
  for (int s = 0; s < 2; ++s)
#pragma unroll
    for (int mt = 0; mt < 2; ++mt)
#pragma unroll
      for (int kc = 0; kc < 2; ++kc) {
        const int row = q0 + wid * 32 + mt * 16 + r;
        qf[s][mt][kc] =
            *(const short8*)&p.Q[s][hbase + (size_t)row * DK + kc * 32 + g * 8];
      }

  // staged-tile registers (T14 split: load early, ds_write after the barrier)
  short8 kst[2][2], vst[2][2];
#pragma unroll
  for (int s = 0; s < 2; ++s) {
    kst[s][0] = *(const short8*)&p.K[s][hbase + (size_t)srow * DK + sch];
    kst[s][1] = *(const short8*)&p.K[s][hbase + (size_t)(srow + 32) * DK + sch];
  }

  float sums[2][2][4];
#pragma unroll
  for (int s = 0; s < 2; ++s)
#pragma unroll
    for (int mt = 0; mt < 2; ++mt)
#pragma unroll
      for (int i = 0; i < 4; ++i) sums[s][mt][i] = 0.f;

  // ---- pass 1: per-row sums of 2^score for both streams ----
  for (int kt = 0; kt < 16; ++kt) {
    if (kt) {                       // previous tile's readers are done
      SCHED_FENCE(); BARRIER(); SCHED_FENCE();
    }
#pragma unroll
    for (int s = 0; s < 2; ++s) {   // vmcnt wait happens here, on kst only
      *(short8*)&Ks[s][srow * 72 + sch] = kst[s][0];
      *(short8*)&Ks[s][(srow + 32) * 72 + sch] = kst[s][1];
    }
    if (kt < 15) {                  // next tile: in flight across compute
      const size_t k0n = (size_t)(kt + 1) * 64;
#pragma unroll
      for (int s = 0; s < 2; ++s) {
        kst[s][0] = *(const short8*)&p.K[s][hbase + (k0n + srow) * DK + sch];
        kst[s][1] = *(const short8*)&p.K[s][hbase + (k0n + srow + 32) * DK + sch];
      }
    }
    SCHED_FENCE(); LGKM0(); BARRIER(); SCHED_FENCE();   // tile visible to all

#pragma unroll
    for (int s = 0; s < 2; ++s) {
#pragma unroll
      for (int nt = 0; nt < 4; ++nt) {
        const short8 b0 = *(const short8*)&Ks[s][(nt * 16 + r) * 72 + g * 8];
        const short8 b1 = *(const short8*)&Ks[s][(nt * 16 + r) * 72 + 32 + g * 8];
#pragma unroll
        for (int mt = 0; mt < 2; ++mt) {
          floatx4 acc = {0.f, 0.f, 0.f, 0.f};
          acc = mfma_bf16(qf[s][mt][0], b0, acc);
          acc = mfma_bf16(qf[s][mt][1], b1, acc);
#pragma unroll
          for (int i = 0; i < 4; ++i)
            sums[s][mt][i] += __builtin_amdgcn_exp2f(acc[i]);
        }
      }
    }
  }

  // pass-2 tile-0 staged loads: issued now so they fly under the reduction
#pragma unroll
  for (int s = 0; s < 2; ++s) {
    kst[s][0] = *(const short8*)&p.K[s][hbase + (size_t)srow * DK + sch];
    kst[s][1] = *(const short8*)&p.K[s][hbase + (size_t)(srow + 32) * DK + sch];
    vst[s][0] = *(const short8*)&p.Vt[s][hbase + (size_t)srow * S_DIM + sch];
    vst[s][1] = *(const short8*)&p.Vt[s][hbase + (size_t)(srow + 32) * S_DIM + sch];
  }

  // reduce row sums across the 16 col-lanes; lane keeps rows g*4+i.
  float inv[2][2][4];
#pragma unroll
  for (int s = 0; s < 2; ++s)
#pragma unroll
    for (int mt = 0; mt < 2; ++mt)
#pragma unroll
      for (int i = 0; i < 4; ++i) {
        float v = sums[s][mt][i];
        v += __shfl_xor(v, 1);
        v += __shfl_xor(v, 2);
        v += __shfl_xor(v, 4);
        v += __shfl_xor(v, 8);
        inv[s][mt][i] = 1.0f / v;
      }

  floatx4 o[2][2][4];
  const floatx4 z4 = {0.f, 0.f, 0.f, 0.f};
#pragma unroll
  for (int s = 0; s < 2; ++s)
#pragma unroll
    for (int mt = 0; mt < 2; ++mt)
#pragma unroll
      for (int nt = 0; nt < 4; ++nt) o[s][mt][nt] = z4;

  // ---- pass 2: recompute scores, p = max(softmax_r, softmax_f), O += P@V ----
  for (int kt = 0; kt < 16; ++kt) {
    // kt==0 barrier also closes pass-1's last readers of Ks
    SCHED_FENCE(); BARRIER(); SCHED_FENCE();
#pragma unroll
    for (int s = 0; s < 2; ++s) {
      *(short8*)&Ks[s][srow * 72 + sch] = kst[s][0];
      *(short8*)&Ks[s][(srow + 32) * 72 + sch] = kst[s][1];
      *(short8*)&Vs[s][srow * 72 + sch] = vst[s][0];
      *(short8*)&Vs[s][(srow + 32) * 72 + sch] = vst[s][1];
    }
    if (kt < 15) {
      const size_t k0n = (size_t)(kt + 1) * 64;
#pragma unroll
      for (int s = 0; s < 2; ++s) {
        kst[s][0] = *(const short8*)&p.K[s][hbase + (k0n + srow) * DK + sch];
        kst[s][1] = *(const short8*)&p.K[s][hbase + (k0n + srow + 32) * DK + sch];
        vst[s][0] = *(const short8*)&p.Vt[s][hbase + (size_t)srow * S_DIM + k0n + sch];
        vst[s][1] =
            *(const short8*)&p.Vt[s][hbase + (size_t)(srow + 32) * S_DIM + k0n + sch];
      }
    }
    SCHED_FENCE(); LGKM0(); BARRIER(); SCHED_FENCE();

#pragma unroll
    for (int nt = 0; nt < 4; ++nt) {
      const short8 br0 = *(const short8*)&Ks[0][(nt * 16 + r) * 72 + g * 8];
      const short8 br1 = *(const short8*)&Ks[0][(nt * 16 + r) * 72 + 32 + g * 8];
      const short8 bf0 = *(const short8*)&Ks[1][(nt * 16 + r) * 72 + g * 8];
      const short8 bf1 = *(const short8*)&Ks[1][(nt * 16 + r) * 72 + 32 + g * 8];
#pragma unroll
      for (int mt = 0; mt < 2; ++mt) {
        floatx4 ar = {0.f, 0.f, 0.f, 0.f};
        floatx4 af = {0.f, 0.f, 0.f, 0.f};
        ar = mfma_bf16(qf[0][mt][0], br0, ar);
        ar = mfma_bf16(qf[0][mt][1], br1, ar);
        af = mfma_bf16(qf[1][mt][0], bf0, af);
        af = mfma_bf16(qf[1][mt][1], bf1, af);
        const int prow = wid * 32 + mt * 16 + g * 4;
#pragma unroll
        for (int i = 0; i < 4; ++i) {
          const float pr = __builtin_amdgcn_exp2f(ar[i]) * inv[0][mt][i];
          const float pf = __builtin_amdgcn_exp2f(af[i]) * inv[1][mt][i];
          Ps[(prow + i) * 72 + nt * 16 + r] = f32_to_bf16_rne(fmaxf(pr, pf));
        }
      }
    }

    // Ps round-trip is wave-local (wave writes & reads only its own 32 rows):
    // wave-level LDS completion + scheduler fence, no block barrier needed.
    LGKM0();
    SCHED_FENCE();

    // PV: P rows in A-layout, V^T cols in B-layout.
#pragma unroll
    for (int mt = 0; mt < 2; ++mt) {
      const short8 pa0 = *(const short8*)&Ps[(wid * 32 + mt * 16 + r) * 72 + g * 8];
      const short8 pa1 = *(const short8*)&Ps[(wid * 32 + mt * 16 + r) * 72 + 32 + g * 8];
#pragma unroll
      for (int s = 0; s < 2; ++s)
#pragma unroll
        for (int nt = 0; nt < 4; ++nt) {
          const short8 v0 = *(const short8*)&Vs[s][(nt * 16 + r) * 72 + g * 8];
          const short8 v1 = *(const short8*)&Vs[s][(nt * 16 + r) * 72 + 32 + g * 8];
          o[s][mt][nt] = mfma_bf16(pa0, v0, o[s][mt][nt]);
          o[s][mt][nt] = mfma_bf16(pa1, v1, o[s][mt][nt]);
        }
    }
  }

  // write O: [B,S,512] bf16 (heads concatenated -> flat rows for out-proj).
  const int bb = bh >> 3, h = bh & 7;
#pragma unroll
  for (int s = 0; s < 2; ++s) {
    u16* out = p.O[s];
#pragma unroll
    for (int mt = 0; mt < 2; ++mt)
#pragma unroll
      for (int nt = 0; nt < 4; ++nt) {
        const int col = h * 64 + nt * 16 + r;
#pragma unroll
        for (int i = 0; i < 4; ++i) {
          const int row = q0 + wid * 32 + mt * 16 + g * 4 + i;
          out[((size_t)bb * S_DIM + row) * DMODEL + col] =
              f32_to_bf16_rne(o[s][mt][nt][i]);
        }
      }
  }
}

// ---------------------------------------------------------------------------
// Kernel 3: output projections. grid = (64, 4, 2). Writes FP32 into d_out.
// ---------------------------------------------------------------------------
struct OutParams {
  const u16* A[2];
  const u16* W[2];
  const u16* Bias[2];
  float* Out[2];
};

__global__ __launch_bounds__(256) void out_gemm(OutParams p) {
  __shared__ u16 ldsA[128 * 32];
  __shared__ u16 ldsB[128 * 32];
  const int z = blockIdx.z;
  const int m0 = blockIdx.x * 128;
  const int n0 = blockIdx.y * 128;

  floatx4 acc[4][4];
  const floatx4 z4 = {0.f, 0.f, 0.f, 0.f};
#pragma unroll
  for (int i = 0; i < 4; ++i)
#pragma unroll
    for (int j = 0; j < 4; ++j) acc[i][j] = z4;

  gemm128_mainloop(p.A[z], p.W[z], m0, n0, DMODEL, ldsA, ldsB, acc);

  const int tid = threadIdx.x, lane = tid & 63, wid = tid >> 6;
  const int wm = wid >> 1, wn = wid & 1, r = lane & 15, g = lane >> 4;
  const u16* bias = p.Bias[z];
  float* out = p.Out[z];

#pragma unroll
  for (int j = 0; j < 4; ++j) {
    const int c = n0 + wn * 64 + j * 16 + r;
    const float bv = bf16_bits_to_f32(bias[c]);
#pragma unroll
    for (int i = 0; i < 4; ++i) {
      const int row0 = m0 + wm * 64 + i * 16 + g * 4;
#pragma unroll
      for (int ii = 0; ii < 4; ++ii)
        out[(size_t)(row0 + ii) * DMODEL + c] = acc[i][j][ii] + bv;   // FP32 store
    }
  }
}

// ---------------------------------------------------------------------------
extern "C" void kernel_launch(void* const* d_in, const int* in_sizes, int n_in,
                              void* d_out, int out_size, void* d_ws, size_t ws_size,
                              hipStream_t stream) {
  (void)in_sizes; (void)n_in; (void)out_size; (void)ws_size;
  u16* ws = (u16*)d_ws;
  u16* Qr = ws + 0 * SEG;
  u16* Kr = ws + 1 * SEG;
  u16* Vr = ws + 2 * SEG;   // stored transposed [B,H,64,S]
  u16* Qf = ws + 3 * SEG;
  u16* Kf = ws + 4 * SEG;
  u16* Vf = ws + 5 * SEG;   // stored transposed [B,H,64,S]
  u16* Or = ws + 6 * SEG;   // also holds converted X_rgb before attn overwrites
  u16* Of = ws + 7 * SEG;   // also holds converted X_flow
  u16* cW = ws + 8 * SEG;            // 8 x 262144
  u16* cB = cW + 8 * WSEG;           // 8 x 512

  // ---- conversion pre-pass ----
  ConvParams cp;
  int coff = 0;
  for (int i = 0; i < NT_CONV; ++i) {
    cp.src[i] = d_in[i];
    int n;
    if (i < 2) {
      n = (int)SEG;
      cp.dst[i] = (i == 0) ? Or : Of;
    } else {
      const int k = (i - 2) >> 1;
      const int isb = (i - 2) & 1;
      n = isb ? DMODEL : (int)WSEG;
      cp.dst[i] = isb ? (cB + k * DMODEL) : (cW + k * WSEG);
    }
    cp.n[i] = n;
    cp.coff[i] = coff;
    coff += (n + 65535) / 65536;
  }
  cp.coff[NT_CONV] = coff;   // 168 chunks total
  convert_inputs<<<dim3(coff), dim3(256), 0, stream>>>(cp);

  // ---- QKV projections ----
  QkvParams qp;
  qp.X[0] = Or;
  qp.X[1] = Of;
  for (int s = 0; s < 2; ++s)
    for (int wi = 0; wi < 3; ++wi) {
      const int k = s * 3 + wi;
      qp.W[s][wi] = cW + k * WSEG;
      qp.Bias[s][wi] = cB + k * DMODEL;
    }
  qp.Out[0][0] = Qr; qp.Out[0][1] = Kr; qp.Out[0][2] = Vr;
  qp.Out[1][0] = Qf; qp.Out[1][1] = Kf; qp.Out[1][2] = Vf;
  qkv_gemm<<<dim3(64, 12, 2), dim3(256), 0, stream>>>(qp);

  // ---- merged attention (overwrites Or/Of with O) ----
  AttnParams ap;
  ap.Q[0] = Qr; ap.Q[1] = Qf;
  ap.K[0] = Kr; ap.K[1] = Kf;
  ap.Vt[0] = Vr; ap.Vt[1] = Vf;
  ap.O[0] = Or; ap.O[1] = Of;
  attn_merged<<<dim3(512), dim3(256), 0, stream>>>(ap);

  // ---- output projections (fp32 out) ----
  OutParams op;
  op.A[0] = Or; op.A[1] = Of;
  op.W[0] = cW + 6 * WSEG; op.Bias[0] = cB + 6 * DMODEL;
  op.W[1] = cW + 7 * WSEG; op.Bias[1] = cB + 7 * DMODEL;
  op.Out[0] = (float*)d_out;
  op.Out[1] = (float*)d_out + SEG;
  out_gemm<<<dim3(64, 4, 2), dim3(256), 0, stream>>>(op);
}

// Round 3
// 280.669 us; speedup vs baseline: 1.1856x; 1.0173x over previous
//
#include <hip/hip_runtime.h>
#include <hip/hip_bf16.h>

// MultiHeadedAttention2: dual-stream MHA with elementwise-max merge of the two
// softmax attention maps. Inputs fp32 (detected & converted to bf16 in ws);
// internal compute bf16 MFMA; OUTPUT WRITTEN AS FP32 (reference output dtype).
//
// Pipeline (4 dispatches):
//  0) convert_inputs: dtype-probe + convert/copy to bf16 in ws.
//  1) qkv_gemm : 6 projections. Q,K -> [B,H,S,64] bf16, V -> [B,H,64,S] bf16.
//                Q pre-scaled by 0.125*log2(e). 2-phase dbuf mainloop
//                (issue-early global_load_lds, vmcnt(0) after MFMAs).
//                V^T epilogue packs 4 consecutive tokens -> 8B stores.
//  2) attn_merged: two-pass merged softmax. Wave owns 16 q-rows (4096 waves
//                -> 16 waves/CU), KVBLK=32, XOR-swizzled unpadded K/V tiles,
//                T14 reg-staged prefetch + raw-barrier pipeline, XCD swizzle.
//  3) out_gemm : output projections + bias -> d_out (FP32, rgb then flow).

typedef unsigned short u16;
typedef __attribute__((ext_vector_type(8))) short short8;   // 8 x bf16 (4 VGPRs)
typedef __attribute__((ext_vector_type(4))) short s4pack;   // 4 x bf16 (8 B)
typedef __attribute__((ext_vector_type(4))) float floatx4;  // MFMA accumulator

#define B_DIM 8
#define S_DIM 1024
#define H_DIM 8
#define DK 64
#define DMODEL 512
#define NTOK (B_DIM * S_DIM)                 // 8192 tokens
#define SEG ((size_t)NTOK * DMODEL)          // 4194304 elems per tensor
#define WSEG ((size_t)DMODEL * DMODEL)       // 262144 elems per weight

#define SCHED_FENCE() __builtin_amdgcn_sched_barrier(0)
#define LGKM0() asm volatile("s_waitcnt lgkmcnt(0)" ::: "memory")
#define VMCNT0() asm volatile("s_waitcnt vmcnt(0)" ::: "memory")
#define BARRIER() __builtin_amdgcn_s_barrier()

__device__ __forceinline__ floatx4 mfma_bf16(short8 a, short8 b, floatx4 c) {
  return __builtin_amdgcn_mfma_f32_16x16x32_bf16(a, b, c, 0, 0, 0);
}

__device__ __forceinline__ u16 f32_to_bf16_rne(float f) {
  unsigned u = __float_as_uint(f);
  unsigned r = u + 0x7FFFu + ((u >> 16) & 1u);
  return (u16)(r >> 16);
}

__device__ __forceinline__ float bf16_bits_to_f32(u16 u) {
  return __uint_as_float(((unsigned)u) << 16);
}

// async global->LDS, 16B per lane; lds is the wave-uniform base
// (HW deposits lane i at lds + i*16).
__device__ __forceinline__ void async_cp16(const u16* g, u16* lds) {
  __builtin_amdgcn_global_load_lds(
      (__attribute__((address_space(1))) void*)(const_cast<u16*>(g)),
      (__attribute__((address_space(3))) void*)(lds), 16, 0, 0);
}

// ---------------------------------------------------------------------------
// Kernel 0: dtype-detect + convert to bf16.
// ---------------------------------------------------------------------------
#define NT_CONV 18
struct ConvParams {
  const void* src[NT_CONV];
  u16* dst[NT_CONV];
  int n[NT_CONV];
  int coff[NT_CONV + 1];   // prefix sums of chunk counts
};

__global__ __launch_bounds__(256) void convert_inputs(ConvParams p) {
  __shared__ int flag_f32;
  const int blk = blockIdx.x;
  int t = 0;
  while (t + 1 < NT_CONV && blk >= p.coff[t + 1]) ++t;
  const int lc = blk - p.coff[t];
  const int n = p.n[t];
  const int tid = threadIdx.x;

  if (tid < 64) {
    const u16* s = (const u16*)p.src[t];
    int bad = 0;
#pragma unroll
    for (int j = 0; j < 8; ++j) {
      float f = bf16_bits_to_f32(s[tid * 8 + j]);
      bad |= !(fabsf(f) < 1e4f);   // catches huge AND NaN
    }
    bad |= __shfl_xor(bad, 1);
    bad |= __shfl_xor(bad, 2);
    bad |= __shfl_xor(bad, 4);
    bad |= __shfl_xor(bad, 8);
    bad |= __shfl_xor(bad, 16);
    bad |= __shfl_xor(bad, 32);
    if (tid == 0) flag_f32 = bad;
  }
  __syncthreads();
  const int is_f32 = flag_f32;
  const int base = lc * 65536;

  for (int it = 0; it < 32; ++it) {
    const int idx = base + (it * 256 + tid) * 8;
    if (idx + 8 > n) break;
    if (!is_f32) {
      *(short8*)&p.dst[t][idx] = *(const short8*)&((const u16*)p.src[t])[idx];
    } else {
      const float* s = (const float*)p.src[t] + idx;
      short8 o;
#pragma unroll
      for (int j = 0; j < 8; ++j) o[j] = (short)f32_to_bf16_rne(s[j]);
      *(short8*)&p.dst[t][idx] = o;
    }
  }
}

// ---------------------------------------------------------------------------
// 128x128 NT GEMM mainloop, 2-phase LDS double-buffer:
//   issue global_load_lds for tile t+1 into buf^1  (early)
//   ds_read frags + 16 MFMA from buf                (hides load latency)
//   vmcnt(0); s_barrier                             (late drain, ~350cy after)
// C += A[m0:+128,:K] * W[n0:+128,:K]^T. A,W row-major bf16, lda=ldw=K.
// ldsA/ldsB are [2][128*32] u16.
// ---------------------------------------------------------------------------
__device__ __forceinline__ void gemm128_mainloop(
    const u16* __restrict__ A, const u16* __restrict__ W,
    int m0, int n0, int K, u16* ldsA, u16* ldsB, floatx4 acc[4][4]) {
  const int tid = threadIdx.x;
  const int lane = tid & 63;
  const int wid = tid >> 6;
  const int wm = wid >> 1, wn = wid & 1;
  const int r = lane & 15, g = lane >> 4;

  const int stg_row = wid * 32 + (lane >> 2);
  const int stg_col = (lane & 3) * 8;

  const u16* ga0 = A + (size_t)(m0 + stg_row) * K + stg_col;
  const u16* ga1 = A + (size_t)(m0 + stg_row + 16) * K + stg_col;
  const u16* gb0 = W + (size_t)(n0 + stg_row) * K + stg_col;
  const u16* gb1 = W + (size_t)(n0 + stg_row + 16) * K + stg_col;
  const int lo0 = (wid * 32) * 32;        // wave-uniform LDS offsets
  const int lo1 = (wid * 32 + 16) * 32;

  // prologue: stage k0=0 into buffer 0
  async_cp16(ga0, ldsA + lo0);
  async_cp16(ga1, ldsA + lo1);
  async_cp16(gb0, ldsB + lo0);
  async_cp16(gb1, ldsB + lo1);
  VMCNT0();
  BARRIER();

  int cur = 0;
  for (int k0 = 0; k0 < K; k0 += 32) {
    const int nxt = cur ^ 1;
    const bool more = (k0 + 32 < K);
    if (more) {            // issue next tile early; buf nxt was freed by the
      const int nb = nxt * 4096;          // barrier at the end of last iter
      async_cp16(ga0 + k0 + 32, ldsA + nb + lo0);
      async_cp16(ga1 + k0 + 32, ldsA + nb + lo1);
      async_cp16(gb0 + k0 + 32, ldsB + nb + lo0);
      async_cp16(gb1 + k0 + 32, ldsB + nb + lo1);
    }
    const int cb = cur * 4096;
    short8 a[4], b[4];
#pragma unroll
    for (int i = 0; i < 4; ++i)
      a[i] = *(const short8*)&ldsA[cb + (wm * 64 + i * 16 + r) * 32 + g * 8];
#pragma unroll
    for (int j = 0; j < 4; ++j)
      b[j] = *(const short8*)&ldsB[cb + (wn * 64 + j * 16 + r) * 32 + g * 8];
#pragma unroll
    for (int i = 0; i < 4; ++i)
#pragma unroll
      for (int j = 0; j < 4; ++j)
        acc[i][j] = mfma_bf16(a[i], b[j], acc[i][j]);
    if (more) {
      SCHED_FENCE(); VMCNT0(); BARRIER(); SCHED_FENCE();
      cur = nxt;
    }
  }
}

// ---------------------------------------------------------------------------
// Kernel 1: QKV projections. grid = (64, 12, 2).
// ---------------------------------------------------------------------------
struct QkvParams {
  const u16* X[2];
  const u16* W[2][3];
  const u16* Bias[2][3];
  u16* Out[2][3];
};

__global__ __launch_bounds__(256) void qkv_gemm(QkvParams p) {
  __shared__ u16 ldsA[2 * 128 * 32];
  __shared__ u16 ldsB[2 * 128 * 32];
  const int z = blockIdx.z;
  const int wi = blockIdx.y >> 2;            // 0=Q 1=K 2=V
  const int n0 = (blockIdx.y & 3) * 128;
  const int m0 = blockIdx.x * 128;

  floatx4 acc[4][4];
  const floatx4 z4 = {0.f, 0.f, 0.f, 0.f};
#pragma unroll
  for (int i = 0; i < 4; ++i)
#pragma unroll
    for (int j = 0; j < 4; ++j) acc[i][j] = z4;

  gemm128_mainloop(p.X[z], p.W[z][wi], m0, n0, DMODEL, ldsA, ldsB, acc);

  const int tid = threadIdx.x, lane = tid & 63, wid = tid >> 6;
  const int wm = wid >> 1, wn = wid & 1, r = lane & 15, g = lane >> 4;
  const u16* bias = p.Bias[z][wi];
  u16* out = p.Out[z][wi];
  const float qscale = 0.125f * 1.4426950408889634f;  // 1/sqrt(dk) * log2(e)

#pragma unroll
  for (int j = 0; j < 4; ++j) {
    const int c = n0 + wn * 64 + j * 16 + r;          // output col in [0,512)
    const float bv = bf16_bits_to_f32(bias[c]);
    const int h = c >> 6, d = c & 63;
#pragma unroll
    for (int i = 0; i < 4; ++i) {
      const int row0 = m0 + wm * 64 + i * 16 + g * 4; // 4 consecutive tokens
      const int bb = row0 >> 10, ss0 = row0 & 1023;
      if (wi == 2) {
        // V^T: [B,H,64,S]. 4 consecutive ss at fixed d -> one 8B store.
        s4pack pk;
#pragma unroll
        for (int ii = 0; ii < 4; ++ii)
          pk[ii] = (short)f32_to_bf16_rne(acc[i][j][ii] + bv);
        *(s4pack*)&out[(((size_t)(bb * H_DIM + h)) * DK + d) * S_DIM + ss0] = pk;
      } else {
#pragma unroll
        for (int ii = 0; ii < 4; ++ii) {
          float v = acc[i][j][ii] + bv;
          if (wi == 0) v *= qscale;                   // Q: pre-scaled
          out[(((size_t)(bb * H_DIM + h)) * S_DIM + (ss0 + ii)) * DK + d] =
              f32_to_bf16_rne(v);
        }
      }
    }
  }
}

// ---------------------------------------------------------------------------
// Kernel 2: merged-softmax attention. grid = (1024) 1-D, XCD-chunked swizzle.
// Per block: 64 q rows of one (b,h); 4 waves; wave w owns rows [w*16,w*16+16).
// -> 4096 waves total = 16 waves/CU (vs 8 before): the occupancy lever.
//
// K/V LDS tiles UNPADDED with XOR-swizzled 16B chunks (write & read same
// swizzle) -> <=2-way bank aliasing on all b128 ops. KVBLK=32.
//
// Per K-tile pipeline (T14): [raw s_barrier] -> ds_write staged regs (implicit
// counted vmcnt on those regs only) -> issue next tile's global loads ->
// lgkmcnt(0) -> [raw s_barrier] -> compute (loads for t+1 land underneath).
// ---------------------------------------------------------------------------
#define KVB 32
#define QB 64

struct AttnParams {
  const u16* Q[2];
  const u16* K[2];
  const u16* Vt[2];
  u16* O[2];
};

__global__ __launch_bounds__(256, 4) void attn_merged(AttnParams p) {
  __shared__ u16 Ks[2][KVB * 64];   // [stream][key][d], chunk-swizzled
  __shared__ u16 Vs[2][64 * KVB];   // [stream][d][key], chunk-swizzled
  __shared__ u16 Ps[QB * 40];       // merged probs [q][key pad40] (wave-local)

  const int tid = threadIdx.x;
  const int lane = tid & 63;
  const int wid = tid >> 6;
  const int r = lane & 15, g = lane >> 4;

  // XCD-chunked bijective swizzle (1024 = 8 XCD * 128): each XCD gets 128
  // consecutive work items = 8 whole heads -> K/V set ~4MB/XCD fits its L2.
  const int lin = blockIdx.x;
  const int w = (lin & 7) * 128 + (lin >> 3);
  const int bh = w >> 4;                 // (b*8+h)
  const int q0 = (w & 15) * QB;          // q-tile base
  const size_t hbase = (size_t)bh * S_DIM * DK;

  // K staging: thread -> (krow in [0,32), chunk kch in [0,8)); LDS chunk
  // XOR-swizzled by krow so frag reads (chunk kc*4+g at row nt*16+r) are
  // conflict-free. Global read stays contiguous (swizzle on LDS side only —
  // legal because staging is reg->ds_write, not global_load_lds).
  const int krow = tid >> 3, kch = tid & 7;
  const int kdst = krow * 64 + ((kch ^ (krow & 7)) * 8);
  const size_t kgsrc = (size_t)krow * DK + kch * 8;
  // V staging: thread -> (vrow=d in [0,64), chunk vch in [0,4))
  const int vrow = tid >> 2, vch = tid & 3;
  const int vdst = vrow * KVB + ((vch ^ ((vrow >> 2) & 3)) * 8);
  const size_t vgsrc = (size_t)vrow * S_DIM + vch * 8;

  // Q fragments (A-operand): lane holds Q[q0+wid*16+r][kc*32+g*8+j]
  short8 qf[2][2];
#pragma unroll
  for (int s = 0; s < 2; ++s)
#pragma unroll
    for (int kc = 0; kc < 2; ++kc)
      qf[s][kc] = *(const short8*)
          &p.Q[s][hbase + (size_t)(q0 + wid * 16 + r) * DK + kc * 32 + g * 8];

  // tile-0 K prefetch
  short8 kst[2], vst[2];
#pragma unroll
  for (int s = 0; s < 2; ++s)
    kst[s] = *(const short8*)&p.K[s][hbase + kgsrc];

  float sums[2][4];
#pragma unroll
  for (int s = 0; s < 2; ++s)
#pragma unroll
    for (int i = 0; i < 4; ++i) sums[s][i] = 0.f;

  // ---- pass 1: per-row sums of 2^score for both streams ----
  for (int kt = 0; kt < 32; ++kt) {
    if (kt) { SCHED_FENCE(); BARRIER(); SCHED_FENCE(); }
#pragma unroll
    for (int s = 0; s < 2; ++s)       // implicit counted vmcnt on kst only
      *(short8*)&Ks[s][kdst] = kst[s];
    if (kt < 31) {
      const size_t k0n = (size_t)(kt + 1) * KVB * DK;
#pragma unroll
      for (int s = 0; s < 2; ++s)
        kst[s] = *(const short8*)&p.K[s][hbase + k0n + kgsrc];
    }
    SCHED_FENCE(); LGKM0(); BARRIER(); SCHED_FENCE();

#pragma unroll
    for (int s = 0; s < 2; ++s)
#pragma unroll
      for (int nt = 0; nt < 2; ++nt) {
        const int row = nt * 16 + r;
        const short8 b0 = *(const short8*)&Ks[s][row * 64 + ((g ^ (r & 7)) * 8)];
        const short8 b1 =
            *(const short8*)&Ks[s][row * 64 + (((4 + g) ^ (r & 7)) * 8)];
        floatx4 acc = {0.f, 0.f, 0.f, 0.f};
        acc = mfma_bf16(qf[s][0], b0, acc);
        acc = mfma_bf16(qf[s][1], b1, acc);
#pragma unroll
        for (int i = 0; i < 4; ++i)
          sums[s][i] += __builtin_amdgcn_exp2f(acc[i]);
      }
  }

  // pass-2 tile-0 staged loads: issued now so they fly under the reduction
#pragma unroll
  for (int s = 0; s < 2; ++s) {
    kst[s] = *(const short8*)&p.K[s][hbase + kgsrc];
    vst[s] = *(const short8*)&p.Vt[s][hbase + vgsrc];
  }

  // reduce row sums across the 16 col-lanes; lane keeps rows g*4+i.
  float inv_[2][4];
#pragma unroll
  for (int s = 0; s < 2; ++s)
#pragma unroll
    for (int i = 0; i < 4; ++i) {
      float v = sums[s][i];
      v += __shfl_xor(v, 1);
      v += __shfl_xor(v, 2);
      v += __shfl_xor(v, 4);
      v += __shfl_xor(v, 8);
      inv_[s][i] = 1.0f / v;
    }

  floatx4 o_[2][4];
  const floatx4 z4 = {0.f, 0.f, 0.f, 0.f};
#pragma unroll
  for (int s = 0; s < 2; ++s)
#pragma unroll
    for (int nt = 0; nt < 4; ++nt) o_[s][nt] = z4;

  // ---- pass 2: recompute scores, p = max(softmax_r, softmax_f), O += P@V ----
  for (int kt = 0; kt < 32; ++kt) {
    // kt==0 barrier also closes pass-1's last readers of Ks
    SCHED_FENCE(); BARRIER(); SCHED_FENCE();
#pragma unroll
    for (int s = 0; s < 2; ++s) {
      *(short8*)&Ks[s][kdst] = kst[s];
      *(short8*)&Vs[s][vdst] = vst[s];
    }
    if (kt < 31) {
      const size_t kn = (size_t)(kt + 1) * KVB;
#pragma unroll
      for (int s = 0; s < 2; ++s) {
        kst[s] = *(const short8*)&p.K[s][hbase + kn * DK + kgsrc];
        vst[s] = *(const short8*)&p.Vt[s][hbase + vgsrc + kn];
      }
    }
    SCHED_FENCE(); LGKM0(); BARRIER(); SCHED_FENCE();

#pragma unroll
    for (int nt = 0; nt < 2; ++nt) {
      const int row = nt * 16 + r;
      const short8 br0 = *(const short8*)&Ks[0][row * 64 + ((g ^ (r & 7)) * 8)];
      const short8 br1 =
          *(const short8*)&Ks[0][row * 64 + (((4 + g) ^ (r & 7)) * 8)];
      const short8 bf0 = *(const short8*)&Ks[1][row * 64 + ((g ^ (r & 7)) * 8)];
      const short8 bf1 =
          *(const short8*)&Ks[1][row * 64 + (((4 + g) ^ (r & 7)) * 8)];
      floatx4 ar = {0.f, 0.f, 0.f, 0.f};
      floatx4 af = {0.f, 0.f, 0.f, 0.f};
      ar = mfma_bf16(qf[0][0], br0, ar);
      ar = mfma_bf16(qf[0][1], br1, ar);
      af = mfma_bf16(qf[1][0], bf0, af);
      af = mfma_bf16(qf[1][1], bf1, af);
      const int prow = wid * 16 + g * 4;
#pragma unroll
      for (int i = 0; i < 4; ++i) {
        const float pr = __builtin_amdgcn_exp2f(ar[i]) * inv_[0][i];
        const float pf = __builtin_amdgcn_exp2f(af[i]) * inv_[1][i];
        Ps[(prow + i) * 40 + nt * 16 + r] = f32_to_bf16_rne(fmaxf(pr, pf));
      }
    }

    // Ps round-trip is wave-local (wave writes & reads only its own 16 rows):
    // wave-level LDS completion + scheduler fence, no block barrier needed.
    LGKM0();
    SCHED_FENCE();

    // PV: P rows in A-layout (k=32 -> single fragment), V^T cols in B-layout.
    const short8 pa = *(const short8*)&Ps[(wid * 16 + r) * 40 + g * 8];
#pragma unroll
    for (int s = 0; s < 2; ++s)
#pragma unroll
      for (int nt = 0; nt < 4; ++nt) {
        const int vr = nt * 16 + r;
        const short8 v = *(const short8*)
            &Vs[s][vr * KVB + ((g ^ ((r >> 2) & 3)) * 8)];
        o_[s][nt] = mfma_bf16(pa, v, o_[s][nt]);
      }
  }

  // write O: [B,S,512] bf16 (heads concatenated -> flat rows for out-proj).
  const int bb = bh >> 3, h = bh & 7;
#pragma unroll
  for (int s = 0; s < 2; ++s) {
    u16* out = p.O[s];
#pragma unroll
    for (int nt = 0; nt < 4; ++nt) {
      const int col = h * 64 + nt * 16 + r;
#pragma unroll
      for (int i = 0; i < 4; ++i) {
        const int row = q0 + wid * 16 + g * 4 + i;
        out[((size_t)bb * S_DIM + row) * DMODEL + col] =
            f32_to_bf16_rne(o_[s][nt][i]);
      }
    }
  }
}

// ---------------------------------------------------------------------------
// Kernel 3: output projections. grid = (64, 4, 2). Writes FP32 into d_out.
// ---------------------------------------------------------------------------
struct OutParams {
  const u16* A[2];
  const u16* W[2];
  const u16* Bias[2];
  float* Out[2];
};

__global__ __launch_bounds__(256) void out_gemm(OutParams p) {
  __shared__ u16 ldsA[2 * 128 * 32];
  __shared__ u16 ldsB[2 * 128 * 32];
  const int z = blockIdx.z;
  const int m0 = blockIdx.x * 128;
  const int n0 = blockIdx.y * 128;

  floatx4 acc[4][4];
  const floatx4 z4 = {0.f, 0.f, 0.f, 0.f};
#pragma unroll
  for (int i = 0; i < 4; ++i)
#pragma unroll
    for (int j = 0; j < 4; ++j) acc[i][j] = z4;

  gemm128_mainloop(p.A[z], p.W[z], m0, n0, DMODEL, ldsA, ldsB, acc);

  const int tid = threadIdx.x, lane = tid & 63, wid = tid >> 6;
  const int wm = wid >> 1, wn = wid & 1, r = lane & 15, g = lane >> 4;
  const u16* bias = p.Bias[z];
  float* out = p.Out[z];

#pragma unroll
  for (int j = 0; j < 4; ++j) {
    const int c = n0 + wn * 64 + j * 16 + r;
    const float bv = bf16_bits_to_f32(bias[c]);
#pragma unroll
    for (int i = 0; i < 4; ++i) {
      const int row0 = m0 + wm * 64 + i * 16 + g * 4;
#pragma unroll
      for (int ii = 0; ii < 4; ++ii)
        out[(size_t)(row0 + ii) * DMODEL + c] = acc[i][j][ii] + bv;   // FP32
    }
  }
}

// ---------------------------------------------------------------------------
extern "C" void kernel_launch(void* const* d_in, const int* in_sizes, int n_in,
                              void* d_out, int out_size, void* d_ws, size_t ws_size,
                              hipStream_t stream) {
  (void)in_sizes; (void)n_in; (void)out_size; (void)ws_size;
  u16* ws = (u16*)d_ws;
  u16* Qr = ws + 0 * SEG;
  u16* Kr = ws + 1 * SEG;
  u16* Vr = ws + 2 * SEG;   // stored transposed [B,H,64,S]
  u16* Qf = ws + 3 * SEG;
  u16* Kf = ws + 4 * SEG;
  u16* Vf = ws + 5 * SEG;   // stored transposed [B,H,64,S]
  u16* Or = ws + 6 * SEG;   // also holds converted X_rgb before attn overwrites
  u16* Of = ws + 7 * SEG;   // also holds converted X_flow
  u16* cW = ws + 8 * SEG;            // 8 x 262144
  u16* cB = cW + 8 * WSEG;           // 8 x 512

  // ---- conversion pre-pass ----
  ConvParams cp;
  int coff = 0;
  for (int i = 0; i < NT_CONV; ++i) {
    cp.src[i] = d_in[i];
    int n;
    if (i < 2) {
      n = (int)SEG;
      cp.dst[i] = (i == 0) ? Or : Of;
    } else {
      const int k = (i - 2) >> 1;
      const int isb = (i - 2) & 1;
      n = isb ? DMODEL : (int)WSEG;
      cp.dst[i] = isb ? (cB + k * DMODEL) : (cW + k * WSEG);
    }
    cp.n[i] = n;
    cp.coff[i] = coff;
    coff += (n + 65535) / 65536;
  }
  cp.coff[NT_CONV] = coff;   // 168 chunks total
  convert_inputs<<<dim3(coff), dim3(256), 0, stream>>>(cp);

  // ---- QKV projections ----
  QkvParams qp;
  qp.X[0] = Or;
  qp.X[1] = Of;
  for (int s = 0; s < 2; ++s)
    for (int wi = 0; wi < 3; ++wi) {
      const int k = s * 3 + wi;
      qp.W[s][wi] = cW + k * WSEG;
      qp.Bias[s][wi] = cB + k * DMODEL;
    }
  qp.Out[0][0] = Qr; qp.Out[0][1] = Kr; qp.Out[0][2] = Vr;
  qp.Out[1][0] = Qf; qp.Out[1][1] = Kf; qp.Out[1][2] = Vf;
  qkv_gemm<<<dim3(64, 12, 2), dim3(256), 0, stream>>>(qp);

  // ---- merged attention (overwrites Or/Of with O) ----
  AttnParams ap;
  ap.Q[0] = Qr; ap.Q[1] = Qf;
  ap.K[0] = Kr; ap.K[1] = Kf;
  ap.Vt[0] = Vr; ap.Vt[1] = Vf;
  ap.O[0] = Or; ap.O[1] = Of;
  attn_merged<<<dim3(1024), dim3(256), 0, stream>>>(ap);

  // ---- output projections (fp32 out) ----
  OutParams op;
  op.A[0] = Or; op.A[1] = Of;
  op.W[0] = cW + 6 * WSEG; op.Bias[0] = cB + 6 * DMODEL;
  op.W[1] = cW + 7 * WSEG; op.Bias[1] = cB + 7 * DMODEL;
  op.Out[0] = (float*)d_out;
  op.Out[1] = (float*)d_out + SEG;
  out_gemm<<<dim3(64, 4, 2), dim3(256), 0, stream>>>(op);
}